// Round 11
// baseline (240.136 us; speedup 1.0000x reference)
//
#include <hip/hip_runtime.h>

#define N_NODES 50000
#define N_EDGES 800000
#define D 256

#define E4 (N_EDGES / 4)                       // 200000
#define BCAP 64                                // bucket slots/row; P(deg>64) ~ 1e-15 (Poisson 16)

// XCD-sliced scatter geometry (blocks [0, SCB) of the fused prep kernel)
#define NSLICE 8
#define SLICE_ROWS (N_NODES / NSLICE)          // 6250 (exact)
#define SCB 2048                               // scatter blocks: 8 slices x 256 wgs
#define SC_WGS (SCB / NSLICE)                  // 256 workgroups per slice
#define SC_CHUNK ((E4 + SC_WGS - 1) / SC_WGS)  // 782 int4-groups per wg

#define XBLKS ((N_NODES * D / 4 + 255) / 256)  // 12500 convert-x blocks (exact)
#define WBLKS (D * D / 256)                    // 256 convert-W blocks
#define PGRID (SCB + XBLKS + WBLKS)            // 14804 prep blocks

#define MT_BLOCKS ((N_NODES + 63) / 64)        // 782 fused agg+gemm blocks (64-row M-tiles)

typedef __attribute__((ext_vector_type(8))) short short8;
typedef __attribute__((ext_vector_type(4))) float f32x4;

typedef const __attribute__((address_space(1))) unsigned int* as1_u32p;
typedef __attribute__((address_space(3))) unsigned int* as3_u32p;

__device__ __forceinline__ unsigned short f2bf(float f) {
    unsigned int u = __float_as_uint(f);
    u = (u + 0x7fffu + ((u >> 16) & 1u)) >> 16;   // RTNE
    return (unsigned short)u;
}

// --- fused prep: bucketed scatter + convert x + convert/transpose W ------
__global__ __launch_bounds__(256) void prep_kernel(const int4* __restrict__ erow4,
                                                   const int4* __restrict__ ecol4,
                                                   const float4* __restrict__ evals4,
                                                   const float4* __restrict__ x,
                                                   ushort4* __restrict__ xh,
                                                   const float* __restrict__ W,
                                                   unsigned short* __restrict__ Wt,
                                                   int* __restrict__ count,
                                                   int2* __restrict__ spay) {
    int b = blockIdx.x;
    if (b < SCB) {
        int sl   = b & (NSLICE - 1);
        int wi   = b >> 3;
        int lo   = sl * SLICE_ROWS;
        int hi   = lo + SLICE_ROWS;
        int base = wi * SC_CHUNK;
        int end  = base + SC_CHUNK;
        if (end > E4) end = E4;

        for (int i = base + (int)threadIdx.x; i < end; i += 256) {
            int4 r = erow4[i];
            bool m0 = (r.x >= lo) & (r.x < hi);
            bool m1 = (r.y >= lo) & (r.y < hi);
            bool m2 = (r.z >= lo) & (r.z < hi);
            bool m3 = (r.w >= lo) & (r.w < hi);
            if (m0 | m1 | m2 | m3) {
                int4   c = ecol4[i];
                float4 v = evals4[i];
                if (m0) { int p = atomicAdd(&count[r.x], 1); if (p < BCAP) spay[r.x * BCAP + p] = make_int2(c.x, __float_as_int(v.x)); }
                if (m1) { int p = atomicAdd(&count[r.y], 1); if (p < BCAP) spay[r.y * BCAP + p] = make_int2(c.y, __float_as_int(v.y)); }
                if (m2) { int p = atomicAdd(&count[r.z], 1); if (p < BCAP) spay[r.z * BCAP + p] = make_int2(c.z, __float_as_int(v.z)); }
                if (m3) { int p = atomicAdd(&count[r.w], 1); if (p < BCAP) spay[r.w * BCAP + p] = make_int2(c.w, __float_as_int(v.w)); }
            }
        }
    } else if (b < SCB + XBLKS) {
        int i = (b - SCB) * 256 + threadIdx.x;   // exactly N_NODES*D/4
        float4 v = x[i];
        xh[i] = make_ushort4(f2bf(v.x), f2bf(v.y), f2bf(v.z), f2bf(v.w));
    } else {
        int idx = (b - SCB - XBLKS) * 256 + threadIdx.x;  // D*D
        int k = idx >> 8, n = idx & 255;
        Wt[n * 256 + k] = f2bf(W[idx]);
    }
}

// --- FUSED aggregate + GEMM: one 64-row M-tile per block -----------------
// Phase 1: 8 waves aggregate 8 rows each (R9-proven depth-12 gather loop)
//          into LDS As[64][256] bf16, XOR-swizzled (byte ^= (row&7)<<4) so
//          the gemm's b128 reads at row-stride 512B don't 16-way conflict.
// Phase 2: 64x256 GEMM vs Wt (Bs staged 16KB per BK=32 step), bias+relu,
//          direct to out. Kills the aggh round-trip (25.6W + 51.2R MB) and
//          one dispatch boundary; agg/gemm phases overlap across blocks.
__global__ __launch_bounds__(512, 6) void agg_gemm(const unsigned short* __restrict__ xh,
                                                   const int* __restrict__ count,
                                                   const int2* __restrict__ spay,
                                                   const unsigned short* __restrict__ Wt,
                                                   const float* __restrict__ bias,
                                                   float* __restrict__ out) {
    __shared__ unsigned short As[64 * 256];   // 32 KB (swizzled)
    __shared__ unsigned short Bs[256 * 32];   // 16 KB

    int tid  = threadIdx.x;
    int wid  = tid >> 6;
    int lane = tid & 63;
    int m0   = blockIdx.x * 64;

    // ---- Phase 1: aggregate ----
#pragma unroll 1
    for (int j = 0; j < 8; ++j) {
        int rl  = wid * 8 + j;                 // local row 0..63
        int row = m0 + rl;
        float a0 = 0.f, a1 = 0.f, a2 = 0.f, a3 = 0.f;
        if (row < N_NODES) {
            int s = row * BCAP;
            int c = count[row];
            if (c > BCAP) c = BCAP;
            int e = s + c;
            int i = s;
            for (; i + 12 <= e; i += 12) {
                int2 p[12];
                uint2 q[12];
#pragma unroll
                for (int t = 0; t < 12; ++t) p[t] = spay[i + t];
#pragma unroll
                for (int t = 0; t < 12; ++t)
                    q[t] = ((const uint2*)(xh + (size_t)p[t].x * D))[lane];
#pragma unroll
                for (int t = 0; t < 12; ++t) {
                    float v = __int_as_float(p[t].y);
                    a0 += v * __uint_as_float(q[t].x << 16);
                    a1 += v * __uint_as_float(q[t].x & 0xffff0000u);
                    a2 += v * __uint_as_float(q[t].y << 16);
                    a3 += v * __uint_as_float(q[t].y & 0xffff0000u);
                }
            }
            for (; i + 4 <= e; i += 4) {
                int2 p[4];
                uint2 q[4];
#pragma unroll
                for (int t = 0; t < 4; ++t) p[t] = spay[i + t];
#pragma unroll
                for (int t = 0; t < 4; ++t)
                    q[t] = ((const uint2*)(xh + (size_t)p[t].x * D))[lane];
#pragma unroll
                for (int t = 0; t < 4; ++t) {
                    float v = __int_as_float(p[t].y);
                    a0 += v * __uint_as_float(q[t].x << 16);
                    a1 += v * __uint_as_float(q[t].x & 0xffff0000u);
                    a2 += v * __uint_as_float(q[t].y << 16);
                    a3 += v * __uint_as_float(q[t].y & 0xffff0000u);
                }
            }
            for (; i < e; ++i) {
                int2  p = spay[i];
                float v = __int_as_float(p.y);
                uint2 q = ((const uint2*)(xh + (size_t)p.x * D))[lane];
                a0 += v * __uint_as_float(q.x << 16);
                a1 += v * __uint_as_float(q.x & 0xffff0000u);
                a2 += v * __uint_as_float(q.y << 16);
                a3 += v * __uint_as_float(q.y & 0xffff0000u);
            }
        }
        // store cols 4*lane..4*lane+3 of local row rl, swizzled
        ushort4 o = make_ushort4(f2bf(a0), f2bf(a1), f2bf(a2), f2bf(a3));
        unsigned bw = (unsigned)rl * 512u + (((unsigned)lane * 8u) ^ (((unsigned)rl & 7u) << 4));
        *(ushort4*)((char*)As + bw) = o;
    }
    __syncthreads();

    // ---- Phase 2: GEMM 64x256 ----
    int wm = wid & 1;        // 2 waves in M (32 rows each)
    int wn = wid >> 1;       // 4 waves in N (64 cols each)
    f32x4 acc[2][4];
#pragma unroll
    for (int i = 0; i < 2; ++i)
#pragma unroll
        for (int j = 0; j < 4; ++j) acc[i][j] = (f32x4){0.f, 0.f, 0.f, 0.f};

    int kq = (lane >> 4) * 8;
    int lm = lane & 15;

    for (int k0 = 0; k0 < D; k0 += 32) {
        // stage Bs[256][32] from Wt rows (n-major): 2 passes x 512 lanes x 16B
#pragma unroll
        for (int it = 0; it < 2; ++it) {
            int idx  = it * 512 + tid;
            int n    = idx >> 2;
            int koff = (idx & 3) * 8;
            const unsigned short* gp = Wt + (size_t)n * D + k0 + koff;
            __builtin_amdgcn_global_load_lds((as1_u32p)gp, (as3_u32p)(Bs + n * 32 + koff), 16, 0, 0);
        }
        __syncthreads();

        short8 af[2], bf[4];
#pragma unroll
        for (int mt = 0; mt < 2; ++mt) {
            unsigned rl = (unsigned)(wm * 32 + mt * 16 + lm);
            unsigned br = rl * 512u + ((((unsigned)(k0 + kq)) * 2u) ^ ((rl & 7u) << 4));
            af[mt] = *(const short8*)((const char*)As + br);
        }
#pragma unroll
        for (int nt = 0; nt < 4; ++nt)
            bf[nt] = *(const short8*)(Bs + (wn * 64 + nt * 16 + lm) * 32 + kq);
#pragma unroll
        for (int mt = 0; mt < 2; ++mt)
#pragma unroll
            for (int nt = 0; nt < 4; ++nt)
                acc[mt][nt] = __builtin_amdgcn_mfma_f32_16x16x32_bf16(af[mt], bf[nt], acc[mt][nt], 0, 0, 0);
        __syncthreads();
    }

    // ---- epilogue: bias + relu ----
    int cl = lane & 15;
    int cr = (lane >> 4) * 4;
#pragma unroll
    for (int nt = 0; nt < 4; ++nt) {
        int n = wn * 64 + nt * 16 + cl;
        float b = bias[n];
#pragma unroll
        for (int mt = 0; mt < 2; ++mt) {
            int mbase = m0 + wm * 32 + mt * 16 + cr;
#pragma unroll
            for (int r = 0; r < 4; ++r) {
                int m = mbase + r;
                if (m < N_NODES) {
                    float v = acc[mt][nt][r] + b;
                    out[(size_t)m * D + n] = v > 0.f ? v : 0.f;
                }
            }
        }
    }
}

extern "C" void kernel_launch(void* const* d_in, const int* in_sizes, int n_in,
                              void* d_out, int out_size, void* d_ws, size_t ws_size,
                              hipStream_t stream) {
    const float* x     = (const float*)d_in[0];
    const int*   erow  = (const int*)d_in[1];
    const int*   ecol  = (const int*)d_in[2];
    const float* evals = (const float*)d_in[3];
    const float* W     = (const float*)d_in[4];
    const float* bias  = (const float*)d_in[5];
    float*       out   = (float*)d_out;

    char* ws = (char*)d_ws;
    unsigned short* xh = (unsigned short*)ws;  ws += (size_t)N_NODES * D * 2;       // 25.6 MB
    int2* spay         = (int2*)ws;            ws += (size_t)N_NODES * BCAP * 8;    // 25.6 MB (was aggh)
    unsigned short* Wt = (unsigned short*)ws;  ws += (size_t)D * D * 2;             // 128 KB
    int* count         = (int*)ws;             ws += (size_t)N_NODES * sizeof(int); // 200 KB

    // zero per-row bucket counters
    hipMemsetAsync(count, 0, (size_t)N_NODES * sizeof(int), stream);

    prep_kernel<<<PGRID, 256, 0, stream>>>(
        (const int4*)erow, (const int4*)ecol, (const float4*)evals,
        (const float4*)x, (ushort4*)xh, W, Wt, count, spay);

    agg_gemm<<<MT_BLOCKS, 512, 0, stream>>>(xh, count, spay, Wt, bias, out);
}

// Round 12
// 231.839 us; speedup vs baseline: 1.0358x; 1.0358x over previous
//
#include <hip/hip_runtime.h>

#define N_NODES 50000
#define N_EDGES 800000
#define D 256

#define E4 (N_EDGES / 4)                       // 200000
#define BCAP 64                                // bucket slots/row; P(deg>64) ~ 1e-15 (Poisson 16)

// XCD-sliced scatter geometry (blocks [0, SCB) of the fused prep kernel)
#define NSLICE 8
#define SLICE_ROWS (N_NODES / NSLICE)          // 6250 (exact)
#define SCB 2048                               // scatter blocks: 8 slices x 256 wgs
#define SC_WGS (SCB / NSLICE)                  // 256 workgroups per slice
#define SC_CHUNK ((E4 + SC_WGS - 1) / SC_WGS)  // 782 int4-groups per wg

#define XBLKS ((N_NODES * D / 4 + 255) / 256)  // 12500 convert-x blocks (exact)
#define WBLKS (D * D / 256)                    // 256 convert-W blocks
#define PGRID (SCB + XBLKS + WBLKS)            // 14804 prep blocks

#define AG_BLOCKS (N_NODES / 2)                // 25000: 2 rows/block, 2 waves/row

typedef __attribute__((ext_vector_type(8))) short short8;
typedef __attribute__((ext_vector_type(4))) float f32x4;

typedef const __attribute__((address_space(1))) unsigned int* as1_u32p;
typedef __attribute__((address_space(3))) unsigned int* as3_u32p;

__device__ __forceinline__ unsigned short f2bf(float f) {
    unsigned int u = __float_as_uint(f);
    u = (u + 0x7fffu + ((u >> 16) & 1u)) >> 16;   // RTNE
    return (unsigned short)u;
}

// --- fused prep: bucketed scatter + convert x + convert/transpose W ------
__global__ __launch_bounds__(256) void prep_kernel(const int4* __restrict__ erow4,
                                                   const int4* __restrict__ ecol4,
                                                   const float4* __restrict__ evals4,
                                                   const float4* __restrict__ x,
                                                   ushort4* __restrict__ xh,
                                                   const float* __restrict__ W,
                                                   unsigned short* __restrict__ Wt,
                                                   int* __restrict__ count,
                                                   int2* __restrict__ spay) {
    int b = blockIdx.x;
    if (b < SCB) {
        int sl   = b & (NSLICE - 1);
        int wi   = b >> 3;
        int lo   = sl * SLICE_ROWS;
        int hi   = lo + SLICE_ROWS;
        int base = wi * SC_CHUNK;
        int end  = base + SC_CHUNK;
        if (end > E4) end = E4;

        for (int i = base + (int)threadIdx.x; i < end; i += 256) {
            int4 r = erow4[i];
            bool m0 = (r.x >= lo) & (r.x < hi);
            bool m1 = (r.y >= lo) & (r.y < hi);
            bool m2 = (r.z >= lo) & (r.z < hi);
            bool m3 = (r.w >= lo) & (r.w < hi);
            if (m0 | m1 | m2 | m3) {
                int4   c = ecol4[i];
                float4 v = evals4[i];
                if (m0) { int p = atomicAdd(&count[r.x], 1); if (p < BCAP) spay[r.x * BCAP + p] = make_int2(c.x, __float_as_int(v.x)); }
                if (m1) { int p = atomicAdd(&count[r.y], 1); if (p < BCAP) spay[r.y * BCAP + p] = make_int2(c.y, __float_as_int(v.y)); }
                if (m2) { int p = atomicAdd(&count[r.z], 1); if (p < BCAP) spay[r.z * BCAP + p] = make_int2(c.z, __float_as_int(v.z)); }
                if (m3) { int p = atomicAdd(&count[r.w], 1); if (p < BCAP) spay[r.w * BCAP + p] = make_int2(c.w, __float_as_int(v.w)); }
            }
        }
    } else if (b < SCB + XBLKS) {
        int i = (b - SCB) * 256 + threadIdx.x;   // exactly N_NODES*D/4
        float4 v = x[i];
        xh[i] = make_ushort4(f2bf(v.x), f2bf(v.y), f2bf(v.z), f2bf(v.w));
    } else {
        int idx = (b - SCB - XBLKS) * 256 + threadIdx.x;  // D*D
        int k = idx >> 8, n = idx & 255;
        Wt[n * 256 + k] = f2bf(W[idx]);
    }
}

// --- Aggregation v3: TWO waves per row (even/odd edges, stride 2) --------
// Same total gather instructions as R9; 2x the waves (TLP discriminator:
// latency-limited -> faster; fabric-pace-limited -> unchanged). Partial
// sums combined via 2KB LDS + one syncthreads. 2 rows per 256-thr block.
__global__ __launch_bounds__(256) void aggregate_kernel(const unsigned short* __restrict__ xh,
                                                        const int* __restrict__ count,
                                                        const int2* __restrict__ spay,
                                                        unsigned short* __restrict__ aggh) {
    __shared__ float4 comb[2][64];
    int tid   = threadIdx.x;
    int wid   = tid >> 6;
    int lane  = tid & 63;
    int rslot = wid >> 1;                 // 0..1: which of the block's 2 rows
    int half  = wid & 1;                  // 0: even edges, 1: odd edges
    int row   = blockIdx.x * 2 + rslot;   // < 50000 exact

    int s = row * BCAP;
    int c = count[row];
    if (c > BCAP) c = BCAP;
    int e = s + c;
    float a0 = 0.f, a1 = 0.f, a2 = 0.f, a3 = 0.f;
    int i = s + half;
    for (; i + 22 < e; i += 24) {         // 12 edges at stride 2
        int2 p[12];
        uint2 q[12];
#pragma unroll
        for (int j = 0; j < 12; ++j) p[j] = spay[i + 2 * j];
#pragma unroll
        for (int j = 0; j < 12; ++j)
            q[j] = ((const uint2*)(xh + (size_t)p[j].x * D))[lane];
#pragma unroll
        for (int j = 0; j < 12; ++j) {
            float v = __int_as_float(p[j].y);
            a0 += v * __uint_as_float(q[j].x << 16);
            a1 += v * __uint_as_float(q[j].x & 0xffff0000u);
            a2 += v * __uint_as_float(q[j].y << 16);
            a3 += v * __uint_as_float(q[j].y & 0xffff0000u);
        }
    }
    for (; i + 6 < e; i += 8) {           // 4 edges at stride 2
        int2 p[4];
        uint2 q[4];
#pragma unroll
        for (int j = 0; j < 4; ++j) p[j] = spay[i + 2 * j];
#pragma unroll
        for (int j = 0; j < 4; ++j)
            q[j] = ((const uint2*)(xh + (size_t)p[j].x * D))[lane];
#pragma unroll
        for (int j = 0; j < 4; ++j) {
            float v = __int_as_float(p[j].y);
            a0 += v * __uint_as_float(q[j].x << 16);
            a1 += v * __uint_as_float(q[j].x & 0xffff0000u);
            a2 += v * __uint_as_float(q[j].y << 16);
            a3 += v * __uint_as_float(q[j].y & 0xffff0000u);
        }
    }
    for (; i < e; i += 2) {
        int2  p = spay[i];
        float v = __int_as_float(p.y);
        uint2 q = ((const uint2*)(xh + (size_t)p.x * D))[lane];
        a0 += v * __uint_as_float(q.x << 16);
        a1 += v * __uint_as_float(q.x & 0xffff0000u);
        a2 += v * __uint_as_float(q.y << 16);
        a3 += v * __uint_as_float(q.y & 0xffff0000u);
    }

    if (half) comb[rslot][lane] = make_float4(a0, a1, a2, a3);
    __syncthreads();
    if (!half) {
        float4 o2 = comb[rslot][lane];
        a0 += o2.x; a1 += o2.y; a2 += o2.z; a3 += o2.w;
        ushort4 o = make_ushort4(f2bf(a0), f2bf(a1), f2bf(a2), f2bf(a3));
        ((ushort4*)(aggh + (size_t)row * D))[lane] = o;
    }
}

// --- GEMM: bf16 MFMA, 128x128 tile, BK=32, fused bias+relu ---------------
__global__ __launch_bounds__(256) void gemm_mfma(const unsigned short* __restrict__ A,
                                                 const unsigned short* __restrict__ Wt,
                                                 const float* __restrict__ bias,
                                                 float* __restrict__ out) {
    __shared__ unsigned short As[128 * 32];
    __shared__ unsigned short Bs[128 * 32];

    int t    = threadIdx.x;
    int w    = t >> 6;
    int lane = t & 63;
    int wm   = w & 1;
    int wn   = w >> 1;
    int mblk = blockIdx.x >> 1;
    int nblk = blockIdx.x & 1;
    int m0   = mblk * 128;
    int n0   = nblk * 128;

    f32x4 acc[4][4];
#pragma unroll
    for (int i = 0; i < 4; ++i)
#pragma unroll
        for (int j = 0; j < 4; ++j) acc[i][j] = (f32x4){0.f, 0.f, 0.f, 0.f};

    int lq = lane >> 2;
    int lr = lane & 3;

    for (int k0 = 0; k0 < D; k0 += 32) {
#pragma unroll
        for (int i = 0; i < 2; ++i) {
            int r0 = i * 64 + w * 16;
            int gm = m0 + r0 + lq;
            if (gm > N_NODES - 1) gm = N_NODES - 1;
            const unsigned short* gp = A + (size_t)gm * D + k0 + lr * 8;
            __builtin_amdgcn_global_load_lds((as1_u32p)gp, (as3_u32p)(As + r0 * 32), 16, 0, 0);
        }
#pragma unroll
        for (int i = 0; i < 2; ++i) {
            int r0 = i * 64 + w * 16;
            int gn = n0 + r0 + lq;
            const unsigned short* gp = Wt + (size_t)gn * D + k0 + lr * 8;
            __builtin_amdgcn_global_load_lds((as1_u32p)gp, (as3_u32p)(Bs + r0 * 32), 16, 0, 0);
        }
        __syncthreads();

        short8 af[4], bf[4];
        int kq = (lane >> 4) * 8;
        int lm = lane & 15;
#pragma unroll
        for (int mt = 0; mt < 4; ++mt)
            af[mt] = *(const short8*)(As + (wm * 64 + mt * 16 + lm) * 32 + kq);
#pragma unroll
        for (int nt = 0; nt < 4; ++nt)
            bf[nt] = *(const short8*)(Bs + (wn * 64 + nt * 16 + lm) * 32 + kq);
#pragma unroll
        for (int mt = 0; mt < 4; ++mt)
#pragma unroll
            for (int nt = 0; nt < 4; ++nt)
                acc[mt][nt] = __builtin_amdgcn_mfma_f32_16x16x32_bf16(af[mt], bf[nt], acc[mt][nt], 0, 0, 0);
        __syncthreads();
    }

    int cl = lane & 15;
    int cr = (lane >> 4) * 4;
#pragma unroll
    for (int nt = 0; nt < 4; ++nt) {
        int n = n0 + wn * 64 + nt * 16 + cl;
        float b = bias[n];
#pragma unroll
        for (int mt = 0; mt < 4; ++mt) {
            int mbase = m0 + wm * 64 + mt * 16 + cr;
#pragma unroll
            for (int r = 0; r < 4; ++r) {
                int m = mbase + r;
                if (m < N_NODES) {
                    float v = acc[mt][nt][r] + b;
                    out[(size_t)m * D + n] = v > 0.f ? v : 0.f;
                }
            }
        }
    }
}

extern "C" void kernel_launch(void* const* d_in, const int* in_sizes, int n_in,
                              void* d_out, int out_size, void* d_ws, size_t ws_size,
                              hipStream_t stream) {
    const float* x     = (const float*)d_in[0];
    const int*   erow  = (const int*)d_in[1];
    const int*   ecol  = (const int*)d_in[2];
    const float* evals = (const float*)d_in[3];
    const float* W     = (const float*)d_in[4];
    const float* bias  = (const float*)d_in[5];
    float*       out   = (float*)d_out;

    char* ws = (char*)d_ws;
    unsigned short* xh   = (unsigned short*)ws;  ws += (size_t)N_NODES * D * 2;   // 25.6 MB
    unsigned short* aggh = (unsigned short*)ws;  ws += (size_t)N_NODES * D * 2;   // 25.6 MB
    unsigned short* Wt   = (unsigned short*)ws;  ws += (size_t)D * D * 2;         // 128 KB
    int* count           = (int*)ws;             ws += (size_t)N_NODES * sizeof(int);

    // bucket payload lives in d_out as scratch (25.6 MB of the 51.2 MB output
    // buffer): fully consumed by aggregate_kernel BEFORE gemm overwrites out.
    int2* spay = (int2*)out;

    // zero per-row bucket counters
    hipMemsetAsync(count, 0, (size_t)N_NODES * sizeof(int), stream);

    prep_kernel<<<PGRID, 256, 0, stream>>>(
        (const int4*)erow, (const int4*)ecol, (const float4*)evals,
        (const float4*)x, (ushort4*)xh, W, Wt, count, spay);

    aggregate_kernel<<<AG_BLOCKS, 256, 0, stream>>>(xh, count, spay, aggh);

    int gblocks = ((N_NODES + 127) / 128) * 2;  // 782
    gemm_mfma<<<gblocks, 256, 0, stream>>>(aggh, Wt, bias, out);
}

// Round 13
// 220.347 us; speedup vs baseline: 1.0898x; 1.0522x over previous
//
#include <hip/hip_runtime.h>

#define N_NODES 50000
#define N_EDGES 800000
#define D 256

#define E4 (N_EDGES / 4)                       // 200000
#define BCAP 64                                // bucket slots/row; P(deg>64) ~ 1e-15 (Poisson 16)

// XCD-sliced scatter geometry (blocks [0, SCB) of the fused prep kernel)
#define NSLICE 8
#define SLICE_ROWS (N_NODES / NSLICE)          // 6250 (exact)
#define SCB 2048                               // scatter blocks: 8 slices x 256 wgs
#define SC_WGS (SCB / NSLICE)                  // 256 workgroups per slice
#define SC_CHUNK ((E4 + SC_WGS - 1) / SC_WGS)  // 782 int4-groups per wg

#define XBLKS ((N_NODES * D / 4 + 255) / 256)  // 12500 convert-x blocks (exact)
#define WBLKS (D * D / 256)                    // 256 convert-W blocks
#define PGRID (SCB + XBLKS + WBLKS)            // 14804 prep blocks

typedef __attribute__((ext_vector_type(8))) short short8;
typedef __attribute__((ext_vector_type(4))) float f32x4;

typedef const __attribute__((address_space(1))) unsigned int* as1_u32p;
typedef __attribute__((address_space(3))) unsigned int* as3_u32p;

__device__ __forceinline__ unsigned short f2bf(float f) {
    unsigned int u = __float_as_uint(f);
    u = (u + 0x7fffu + ((u >> 16) & 1u)) >> 16;   // RTNE
    return (unsigned short)u;
}

// --- fused prep: bucketed scatter + convert x + convert/transpose W ------
// Bucketed scatter (slot = row*BCAP + atomicAdd(count[row])) removes the
// histogram AND the prefix-sum dispatch: scatter, convert-x, convert-W are
// mutually independent, so they share ONE dispatch. Scatter blocks first
// (long pole, XCD-sliced: slice = blockIdx&7 keeps each slice's 3.2MB
// bucket region in one XCD's L2); convert blocks backfill and overlap.
__global__ __launch_bounds__(256) void prep_kernel(const int4* __restrict__ erow4,
                                                   const int4* __restrict__ ecol4,
                                                   const float4* __restrict__ evals4,
                                                   const float4* __restrict__ x,
                                                   ushort4* __restrict__ xh,
                                                   const float* __restrict__ W,
                                                   unsigned short* __restrict__ Wt,
                                                   int* __restrict__ count,
                                                   int2* __restrict__ spay) {
    int b = blockIdx.x;
    if (b < SCB) {
        int sl   = b & (NSLICE - 1);
        int wi   = b >> 3;
        int lo   = sl * SLICE_ROWS;
        int hi   = lo + SLICE_ROWS;
        int base = wi * SC_CHUNK;
        int end  = base + SC_CHUNK;
        if (end > E4) end = E4;

        for (int i = base + (int)threadIdx.x; i < end; i += 256) {
            int4 r = erow4[i];
            bool m0 = (r.x >= lo) & (r.x < hi);
            bool m1 = (r.y >= lo) & (r.y < hi);
            bool m2 = (r.z >= lo) & (r.z < hi);
            bool m3 = (r.w >= lo) & (r.w < hi);
            if (m0 | m1 | m2 | m3) {
                int4   c = ecol4[i];
                float4 v = evals4[i];
                if (m0) { int p = atomicAdd(&count[r.x], 1); if (p < BCAP) spay[r.x * BCAP + p] = make_int2(c.x, __float_as_int(v.x)); }
                if (m1) { int p = atomicAdd(&count[r.y], 1); if (p < BCAP) spay[r.y * BCAP + p] = make_int2(c.y, __float_as_int(v.y)); }
                if (m2) { int p = atomicAdd(&count[r.z], 1); if (p < BCAP) spay[r.z * BCAP + p] = make_int2(c.z, __float_as_int(v.z)); }
                if (m3) { int p = atomicAdd(&count[r.w], 1); if (p < BCAP) spay[r.w * BCAP + p] = make_int2(c.w, __float_as_int(v.w)); }
            }
        }
    } else if (b < SCB + XBLKS) {
        int i = (b - SCB) * 256 + threadIdx.x;   // exactly N_NODES*D/4
        float4 v = x[i];
        xh[i] = make_ushort4(f2bf(v.x), f2bf(v.y), f2bf(v.z), f2bf(v.w));
    } else {
        int idx = (b - SCB - XBLKS) * 256 + threadIdx.x;  // D*D
        int k = idx >> 8, n = idx & 255;
        Wt[n * 256 + k] = f2bf(W[idx]);
    }
}

// --- Aggregation: wave per row over its bucket, depth-12 main loop -------
// At the measured random-gather pace wall: 177MB compulsory per-XCD L2-fill
// at ~3.6TB/s. Depth 8/12 identical (R2/R4), D-half slicing slower (R10),
// 2-wave TLP slower (R12), fusion with gemm slower (R11).
__global__ __launch_bounds__(256) void aggregate_kernel(const unsigned short* __restrict__ xh,
                                                        const int* __restrict__ count,
                                                        const int2* __restrict__ spay,
                                                        unsigned short* __restrict__ aggh) {
    int gid  = blockIdx.x * 256 + threadIdx.x;
    int row  = gid >> 6;
    int lane = threadIdx.x & 63;
    if (row >= N_NODES) return;
    int s = row * BCAP;
    int c = count[row];
    if (c > BCAP) c = BCAP;
    int e = s + c;
    float a0 = 0.f, a1 = 0.f, a2 = 0.f, a3 = 0.f;
    int i = s;
    for (; i + 12 <= e; i += 12) {
        int2 p[12];
        uint2 q[12];
#pragma unroll
        for (int j = 0; j < 12; ++j) p[j] = spay[i + j];
#pragma unroll
        for (int j = 0; j < 12; ++j)
            q[j] = ((const uint2*)(xh + (size_t)p[j].x * D))[lane];
#pragma unroll
        for (int j = 0; j < 12; ++j) {
            float v = __int_as_float(p[j].y);
            a0 += v * __uint_as_float(q[j].x << 16);
            a1 += v * __uint_as_float(q[j].x & 0xffff0000u);
            a2 += v * __uint_as_float(q[j].y << 16);
            a3 += v * __uint_as_float(q[j].y & 0xffff0000u);
        }
    }
    for (; i + 4 <= e; i += 4) {
        int2 p[4];
        uint2 q[4];
#pragma unroll
        for (int j = 0; j < 4; ++j) p[j] = spay[i + j];
#pragma unroll
        for (int j = 0; j < 4; ++j)
            q[j] = ((const uint2*)(xh + (size_t)p[j].x * D))[lane];
#pragma unroll
        for (int j = 0; j < 4; ++j) {
            float v = __int_as_float(p[j].y);
            a0 += v * __uint_as_float(q[j].x << 16);
            a1 += v * __uint_as_float(q[j].x & 0xffff0000u);
            a2 += v * __uint_as_float(q[j].y << 16);
            a3 += v * __uint_as_float(q[j].y & 0xffff0000u);
        }
    }
    for (; i < e; ++i) {
        int2  p = spay[i];
        float v = __int_as_float(p.y);
        uint2 q = ((const uint2*)(xh + (size_t)p.x * D))[lane];
        a0 += v * __uint_as_float(q.x << 16);
        a1 += v * __uint_as_float(q.x & 0xffff0000u);
        a2 += v * __uint_as_float(q.y << 16);
        a3 += v * __uint_as_float(q.y & 0xffff0000u);
    }
    ushort4 o = make_ushort4(f2bf(a0), f2bf(a1), f2bf(a2), f2bf(a3));
    ((ushort4*)(aggh + (size_t)row * D))[lane] = o;
}

// --- GEMM: bf16 MFMA, 128x128 tile, BK=32, fused bias+relu ---------------
__global__ __launch_bounds__(256) void gemm_mfma(const unsigned short* __restrict__ A,
                                                 const unsigned short* __restrict__ Wt,
                                                 const float* __restrict__ bias,
                                                 float* __restrict__ out) {
    __shared__ unsigned short As[128 * 32];
    __shared__ unsigned short Bs[128 * 32];

    int t    = threadIdx.x;
    int w    = t >> 6;
    int lane = t & 63;
    int wm   = w & 1;
    int wn   = w >> 1;
    int mblk = blockIdx.x >> 1;
    int nblk = blockIdx.x & 1;
    int m0   = mblk * 128;
    int n0   = nblk * 128;

    f32x4 acc[4][4];
#pragma unroll
    for (int i = 0; i < 4; ++i)
#pragma unroll
        for (int j = 0; j < 4; ++j) acc[i][j] = (f32x4){0.f, 0.f, 0.f, 0.f};

    int lq = lane >> 2;
    int lr = lane & 3;

    for (int k0 = 0; k0 < D; k0 += 32) {
#pragma unroll
        for (int i = 0; i < 2; ++i) {
            int r0 = i * 64 + w * 16;
            int gm = m0 + r0 + lq;
            if (gm > N_NODES - 1) gm = N_NODES - 1;
            const unsigned short* gp = A + (size_t)gm * D + k0 + lr * 8;
            __builtin_amdgcn_global_load_lds((as1_u32p)gp, (as3_u32p)(As + r0 * 32), 16, 0, 0);
        }
#pragma unroll
        for (int i = 0; i < 2; ++i) {
            int r0 = i * 64 + w * 16;
            int gn = n0 + r0 + lq;
            const unsigned short* gp = Wt + (size_t)gn * D + k0 + lr * 8;
            __builtin_amdgcn_global_load_lds((as1_u32p)gp, (as3_u32p)(Bs + r0 * 32), 16, 0, 0);
        }
        __syncthreads();

        short8 af[4], bf[4];
        int kq = (lane >> 4) * 8;
        int lm = lane & 15;
#pragma unroll
        for (int mt = 0; mt < 4; ++mt)
            af[mt] = *(const short8*)(As + (wm * 64 + mt * 16 + lm) * 32 + kq);
#pragma unroll
        for (int nt = 0; nt < 4; ++nt)
            bf[nt] = *(const short8*)(Bs + (wn * 64 + nt * 16 + lm) * 32 + kq);
#pragma unroll
        for (int mt = 0; mt < 4; ++mt)
#pragma unroll
            for (int nt = 0; nt < 4; ++nt)
                acc[mt][nt] = __builtin_amdgcn_mfma_f32_16x16x32_bf16(af[mt], bf[nt], acc[mt][nt], 0, 0, 0);
        __syncthreads();
    }

    int cl = lane & 15;
    int cr = (lane >> 4) * 4;
#pragma unroll
    for (int nt = 0; nt < 4; ++nt) {
        int n = n0 + wn * 64 + nt * 16 + cl;
        float b = bias[n];
#pragma unroll
        for (int mt = 0; mt < 4; ++mt) {
            int mbase = m0 + wm * 64 + mt * 16 + cr;
#pragma unroll
            for (int r = 0; r < 4; ++r) {
                int m = mbase + r;
                if (m < N_NODES) {
                    float v = acc[mt][nt][r] + b;
                    out[(size_t)m * D + n] = v > 0.f ? v : 0.f;
                }
            }
        }
    }
}

extern "C" void kernel_launch(void* const* d_in, const int* in_sizes, int n_in,
                              void* d_out, int out_size, void* d_ws, size_t ws_size,
                              hipStream_t stream) {
    const float* x     = (const float*)d_in[0];
    const int*   erow  = (const int*)d_in[1];
    const int*   ecol  = (const int*)d_in[2];
    const float* evals = (const float*)d_in[3];
    const float* W     = (const float*)d_in[4];
    const float* bias  = (const float*)d_in[5];
    float*       out   = (float*)d_out;

    char* ws = (char*)d_ws;
    unsigned short* xh   = (unsigned short*)ws;  ws += (size_t)N_NODES * D * 2;   // 25.6 MB
    unsigned short* aggh = (unsigned short*)ws;  ws += (size_t)N_NODES * D * 2;   // 25.6 MB
    unsigned short* Wt   = (unsigned short*)ws;  ws += (size_t)D * D * 2;         // 128 KB
    int* count           = (int*)ws;             ws += (size_t)N_NODES * sizeof(int);

    // bucket payload lives in d_out as scratch (25.6 MB of the 51.2 MB output
    // buffer): fully consumed by aggregate_kernel BEFORE gemm overwrites out.
    int2* spay = (int2*)out;

    // zero per-row bucket counters
    hipMemsetAsync(count, 0, (size_t)N_NODES * sizeof(int), stream);

    prep_kernel<<<PGRID, 256, 0, stream>>>(
        (const int4*)erow, (const int4*)ecol, (const float4*)evals,
        (const float4*)x, (ushort4*)xh, W, Wt, count, spay);

    int ablocks = (N_NODES * 64 + 255) / 256;   // 12500
    aggregate_kernel<<<ablocks, 256, 0, stream>>>(xh, count, spay, aggh);

    int gblocks = ((N_NODES + 127) / 128) * 2;  // 782
    gemm_mfma<<<gblocks, 256, 0, stream>>>(aggh, Wt, bias, out);
}